// Round 15
// baseline (226.673 us; speedup 1.0000x reference)
//
#include <hip/hip_runtime.h>

typedef __attribute__((ext_vector_type(8))) short bf16x8;
typedef __attribute__((ext_vector_type(4))) float f32x4;

// Operand-swapped GEMM: D^T = W (A-operand) * h^T (B-operand).
// r15: 8 waves = {L1, L23} x 4 col-stripes. The L23 wave reads h1+h2+h3 (6
// b128) and computes BOTH L2(i-1) and L3(i-2) -- the h2 tile is read ONCE and
// used as L2-state AND L3-input (r14 read it twice in different waves).
// Per-CU-phase LDS reads 40 -> 32. Arithmetic bit-identical to r14.
#define MFMA(a, b, c) __builtin_amdgcn_mfma_f32_16x16x32_bf16((a), (b), (c), 0, 0, 0)

#define TANH_SCALE 2.8853900817779268f   // 2*log2(e); folded into weights

__device__ __forceinline__ short f2bf(float f) {
    union { float f; unsigned u; } v; v.f = f;
    unsigned r = v.u + 0x7fffu + ((v.u >> 16) & 1u);   // RNE
    return (short)(r >> 16);
}
__device__ __forceinline__ float bf2f(short h) {
    union { unsigned u; float f; } v;
    v.u = ((unsigned)(unsigned short)h) << 16;
    return v.f;
}
__device__ __forceinline__ void wsplit(float w, short& hi, short& lo) {
    hi = f2bf(w);
    lo = f2bf(w - bf2f(hi));
}
// tanh on a PRESCALED accumulator s = 2*log2(e)*y:  tanh(y) = 1 - 2/(2^s + 1)
__device__ __forceinline__ float tanh_ps(float s) {
    float z = __builtin_amdgcn_exp2f(s);
    return fmaf(-2.0f, __builtin_amdgcn_rcpf(z + 1.0f), 1.0f);
}
__device__ __forceinline__ unsigned cvt_pk_bf16(float a, float b) {
    unsigned r;
    asm("v_cvt_pk_bf16_f32 %0, %1, %2" : "=v"(r) : "v"(a), "v"(b));
    return r;
}

// weight fragment pair (hi + bf16 residual) of SCALED weight, zero-padded
__device__ __forceinline__ void makeA2(const float* __restrict__ W, int jrow, int kbase,
                                       bf16x8& Ahi, bf16x8& Alo) {
#pragma unroll
    for (int i = 0; i < 8; ++i) {
        int m = kbase + i;
        short h = 0, l = 0;
        if (jrow < 50 && m < 50) wsplit(W[jrow * 50 + m] * TANH_SCALE, h, l);
        Ahi[i] = h; Alo[i] = l;
    }
}

// --- LDS h tile: [16 batch][128 slot] bf16 (256B rows); cols 0-63 used.
// XOR-swizzle bits 4-7 of byte-in-row with row (bijective). Offsets are
// byte-identical to r13/r14 (lo half unused).
__device__ __forceinline__ int swz(int row, int byteInRow) {
    return (row << 8) + (byteInRow ^ ((row & 15) << 4));
}
__device__ __forceinline__ bf16x8 ldsO(const short* hall, int off) {
    return *(const bf16x8*)((const char*)hall + off);
}
__device__ __forceinline__ float ldsR(const short* buf, int row, int col) {
    return bf2f(*(const short*)((const char*)buf + swz(row, col << 1)));
}

// store 4 consecutive hidden cols (single bf16) at precomputed offset.
__device__ __forceinline__ void storeH(short* hall, int off, float t0, float t1, float t2, float t3) {
    uint2 hv;
    hv.x = cvt_pk_bf16(t0, t1);
    hv.y = cvt_pk_bf16(t2, t3);
    *(uint2*)((char*)hall + off) = hv;
}
__device__ __forceinline__ void storeZ(short* hall, int off) {
    uint2 zz; zz.x = 0u; zz.y = 0u;
    *(uint2*)((char*)hall + off) = zz;
}

// One phase. L1 wave: 2 reads (h1 state), 4 MFMAs, x folded into C-init.
// L23 wave: 6 reads (h1, h2 shared, h3), 12 MFMAs in 4 independent chains of
// 3, two tanh+store tails. ONE barrier at phase end. Per-layer chain order is
// bit-identical to r14. Z2/Z3: pipeline-fill zero stores.
template<bool Z2, bool Z3>
__device__ __forceinline__ void phaseY(
    short* hall, bool isL1,
    int r1a, int r1b, int r2a, int r2b, int r3a, int r3b,
    int wo1, int wo2, int wo3,
    const float* xrow, int bcol,
    const f32x4& b1v, const f32x4& w1f,
    const bf16x8& A1h0, const bf16x8& A1h1, const bf16x8& A1l0, const bf16x8& A1l1,
    const f32x4& bv2, const bf16x8& I2h0, const bf16x8& I2h1,
    const bf16x8& H2h0, const bf16x8& H2h1, const bf16x8& H2l0, const bf16x8& H2l1,
    const f32x4& bv3, const bf16x8& I3h0, const bf16x8& I3h1,
    const bf16x8& H3h0, const bf16x8& H3h1, const bf16x8& H3l0, const bf16x8& H3l1,
    const f32x4& zc)
{
    if (isL1) {
        float xf = xrow[bcol];
        f32x4 c1i;
        c1i[0] = fmaf(w1f[0], xf, b1v[0]);
        c1i[1] = fmaf(w1f[1], xf, b1v[1]);
        c1i[2] = fmaf(w1f[2], xf, b1v[2]);
        c1i[3] = fmaf(w1f[3], xf, b1v[3]);
        bf16x8 s0 = ldsO(hall, r1a), s1 = ldsO(hall, r1b);
        f32x4 c0 = MFMA(A1h0, s0, c1i);
        f32x4 c1 = MFMA(A1h1, s1, zc);
        c0 = MFMA(A1l0, s0, c0);
        c1 = MFMA(A1l1, s1, c1);
        float t0 = tanh_ps(c0[0] + c1[0]);
        float t1 = tanh_ps(c0[1] + c1[1]);
        float t2 = tanh_ps(c0[2] + c1[2]);
        float t3 = tanh_ps(c0[3] + c1[3]);
        storeH(hall, wo1, t0, t1, t2, t3);
    } else {
        bf16x8 i0 = ldsO(hall, r1a), i1 = ldsO(hall, r1b);   // h1: L2 input
        bf16x8 m0 = ldsO(hall, r2a), m1 = ldsO(hall, r2b);   // h2: L2 state + L3 input
        bf16x8 t0v = ldsO(hall, r3a), t1v = ldsO(hall, r3b); // h3: L3 state
        // two layers, 4 independent chains, interleaved for ILP
        f32x4 a0 = MFMA(I2h0, i0, bv2);
        f32x4 b0 = MFMA(I3h0, m0, bv3);
        f32x4 a1 = MFMA(I2h1, i1, zc);
        f32x4 b1 = MFMA(I3h1, m1, zc);
        a0 = MFMA(H2h0, m0, a0);
        b0 = MFMA(H3h0, t0v, b0);
        a1 = MFMA(H2h1, m1, a1);
        b1 = MFMA(H3h1, t1v, b1);
        a0 = MFMA(H2l0, m0, a0);
        b0 = MFMA(H3l0, t0v, b0);
        a1 = MFMA(H2l1, m1, a1);
        b1 = MFMA(H3l1, t1v, b1);
        if (Z2) {
            storeZ(hall, wo2);
        } else {
            float t0 = tanh_ps(a0[0] + a1[0]);
            float t1 = tanh_ps(a0[1] + a1[1]);
            float t2 = tanh_ps(a0[2] + a1[2]);
            float t3 = tanh_ps(a0[3] + a1[3]);
            storeH(hall, wo2, t0, t1, t2, t3);
        }
        if (Z3) {
            storeZ(hall, wo3);
        } else {
            float t0 = tanh_ps(b0[0] + b1[0]);
            float t1 = tanh_ps(b0[1] + b1[1]);
            float t2 = tanh_ps(b0[2] + b1[2]);
            float t3 = tanh_ps(b0[3] + b1[3]);
            storeH(hall, wo3, t0, t1, t2, t3);
        }
    }
    __syncthreads();
}

__global__ __launch_bounds__(512, 1)
void rnn3_kernel(const float* __restrict__ x,
                 const float* __restrict__ Wih1, const float* __restrict__ Whh1,
                 const float* __restrict__ bih1, const float* __restrict__ bhh1,
                 const float* __restrict__ Wih2, const float* __restrict__ Whh2,
                 const float* __restrict__ bih2, const float* __restrict__ bhh2,
                 const float* __restrict__ Wih3, const float* __restrict__ Whh3,
                 const float* __restrict__ bih3, const float* __restrict__ bhh3,
                 const float* __restrict__ Wfc,  const float* __restrict__ bfc,
                 float* __restrict__ out)
{
    // fused state buffer: region r = buf*2 + parity (buf: 0=h1, 1=h2, 2=h3),
    // each region 4096 bytes = [16][128] bf16 swizzled tile (cols 0-63 used).
    __shared__ __align__(16) short hall[6][2048];
    __shared__ float xls[514 * 17 + 8];   // x f32 stride-17; drain tail zeroed

    const int tid  = threadIdx.x;
    const int lane = tid & 63;
    const int w    = tid >> 6;        // 0..7
    const int stripe = w & 3;         // 16-col output stripe
    const bool isL1 = w < 4;          // wave role: L1 vs merged L2+L3
    const int g    = lane >> 4;
    const int l15  = lane & 15;
    const int jrow = (stripe << 4) | l15;      // weight row (output col)
    const int bcol = l15;                      // batch row
    const int jout0 = (stripe << 4) + (g << 2);
    const int b0   = blockIdx.x * 16;

    // ---- zero-init all h regions (h(-1)=0 + fill safety) ----
    { int* z = (int*)hall; for (int k = tid; k < 6144; k += 512) z[k] = 0; }

    // ---- stage x as f32 [t][b] (stride 17); zero the drain tail ----
    {
        const float4* xg = (const float4*)(x + (size_t)b0 * 512);
        for (int idx = tid; idx < 2048; idx += 512) {
            float4 v = xg[idx];
            int b = idx >> 7, t0 = (idx & 127) << 2;
            xls[(t0 + 0) * 17 + b] = v.x;
            xls[(t0 + 1) * 17 + b] = v.y;
            xls[(t0 + 2) * 17 + b] = v.z;
            xls[(t0 + 3) * 17 + b] = v.w;
        }
        if (tid < 42) xls[512 * 17 + tid] = 0.0f;   // covers phases 512/513 reads
    }

    // ---- per-wave weights (prescaled by 2*log2(e)) ----
    bf16x8 zf8 = {0,0,0,0,0,0,0,0};
    bf16x8 A1h0 = zf8, A1h1 = zf8, A1l0 = zf8, A1l1 = zf8;
    bf16x8 I2h0 = zf8, I2h1 = zf8, H2h0 = zf8, H2h1 = zf8, H2l0 = zf8, H2l1 = zf8;
    bf16x8 I3h0 = zf8, I3h1 = zf8, H3h0 = zf8, H3h1 = zf8, H3l0 = zf8, H3l1 = zf8;
    f32x4 b1v = {0.f,0.f,0.f,0.f}, w1f = b1v, bv2 = b1v, bv3 = b1v;

    if (isL1) {
        makeA2(Whh1, jrow, (g << 3),      A1h0, A1l0);
        makeA2(Whh1, jrow, 32 + (g << 3), A1h1, A1l1);
#pragma unroll
        for (int r = 0; r < 4; ++r) {
            int j = jout0 + r;
            bool v = j < 50;
            b1v[r] = v ? ((bih1[j] + bhh1[j]) * TANH_SCALE) : 0.0f;
            w1f[r] = v ? (Wih1[j] * TANH_SCALE) : 0.0f;
        }
    } else {
        bf16x8 d0, d1;   // input-side lo residuals dropped (r12 design)
        makeA2(Wih2, jrow, (g << 3),      I2h0, d0);
        makeA2(Wih2, jrow, 32 + (g << 3), I2h1, d1);
        makeA2(Whh2, jrow, (g << 3),      H2h0, H2l0);
        makeA2(Whh2, jrow, 32 + (g << 3), H2h1, H2l1);
        makeA2(Wih3, jrow, (g << 3),      I3h0, d0);
        makeA2(Wih3, jrow, 32 + (g << 3), I3h1, d1);
        makeA2(Whh3, jrow, (g << 3),      H3h0, H3l0);
        makeA2(Whh3, jrow, 32 + (g << 3), H3h1, H3l1);
#pragma unroll
        for (int r = 0; r < 4; ++r) {
            int j = jout0 + r;
            bool v = j < 50;
            bv2[r] = v ? ((bih2[j] + bhh2[j]) * TANH_SCALE) : 0.0f;
            bv3[r] = v ? ((bih3[j] + bhh3[j]) * TANH_SCALE) : 0.0f;
        }
    }
    const f32x4 zc = {0.f, 0.f, 0.f, 0.f};

    // ---- loop-invariant byte offsets ----
    const int o0 = swz(bcol, (0 << 6) + (g << 4));   // kblk 0
    const int o1 = swz(bcol, (1 << 6) + (g << 4));   // kblk 1
    const int wbyte = swz(bcol, jout0 << 1);
    // A-phase: read parity 1, write parity 0.  B-phase: opposite.
    const int A_r1a = (0*2+1)*4096 + o0, A_r1b = (0*2+1)*4096 + o1;
    const int A_r2a = (1*2+1)*4096 + o0, A_r2b = (1*2+1)*4096 + o1;
    const int A_r3a = (2*2+1)*4096 + o0, A_r3b = (2*2+1)*4096 + o1;
    const int A_w1  = (0*2+0)*4096 + wbyte;
    const int A_w2  = (1*2+0)*4096 + wbyte;
    const int A_w3  = (2*2+0)*4096 + wbyte;
    const int B_r1a = (0*2+0)*4096 + o0, B_r1b = (0*2+0)*4096 + o1;
    const int B_r2a = (1*2+0)*4096 + o0, B_r2b = (1*2+0)*4096 + o1;
    const int B_r3a = (2*2+0)*4096 + o0, B_r3b = (2*2+0)*4096 + o1;
    const int B_w1  = (0*2+1)*4096 + wbyte;
    const int B_w2  = (1*2+1)*4096 + wbyte;
    const int B_w3  = (2*2+1)*4096 + wbyte;

    __syncthreads();   // x staged, h zeroed

    // phase i: reads parity (i+1)&1, writes parity i&1 (r14 schedule).
    // phase 0 (A): L1(0) real; L2/L3 write zeros (= h(-1) states)
    phaseY<true, true>(&hall[0][0], isL1,
                       A_r1a, A_r1b, A_r2a, A_r2b, A_r3a, A_r3b, A_w1, A_w2, A_w3,
                       &xls[0], bcol, b1v, w1f, A1h0, A1h1, A1l0, A1l1,
                       bv2, I2h0, I2h1, H2h0, H2h1, H2l0, H2l1,
                       bv3, I3h0, I3h1, H3h0, H3h1, H3l0, H3l1, zc);
    // phase 1 (B): L1(1), L2(0) real; L3 writes zero
    phaseY<false, true>(&hall[0][0], isL1,
                        B_r1a, B_r1b, B_r2a, B_r2b, B_r3a, B_r3b, B_w1, B_w2, B_w3,
                        &xls[17], bcol, b1v, w1f, A1h0, A1h1, A1l0, A1l1,
                        bv2, I2h0, I2h1, H2h0, H2h1, H2l0, H2l1,
                        bv3, I3h0, I3h1, H3h0, H3h1, H3l0, H3l1, zc);

    // main phases 2..511 (manual 2x unroll, compile-time parities)
    for (int i = 2; i < 512; i += 2) {
        phaseY<false, false>(&hall[0][0], isL1,
                             A_r1a, A_r1b, A_r2a, A_r2b, A_r3a, A_r3b, A_w1, A_w2, A_w3,
                             &xls[i * 17], bcol, b1v, w1f, A1h0, A1h1, A1l0, A1l1,
                             bv2, I2h0, I2h1, H2h0, H2h1, H2l0, H2l1,
                             bv3, I3h0, I3h1, H3h0, H3h1, H3l0, H3l1, zc);
        phaseY<false, false>(&hall[0][0], isL1,
                             B_r1a, B_r1b, B_r2a, B_r2b, B_r3a, B_r3b, B_w1, B_w2, B_w3,
                             &xls[(i + 1) * 17], bcol, b1v, w1f, A1h0, A1h1, A1l0, A1l1,
                             bv2, I2h0, I2h1, H2h0, H2h1, H2l0, H2l1,
                             bv3, I3h0, I3h1, H3h0, H3h1, H3l0, H3l1, zc);
    }

    // drain: phase 512 (A): L2(511), L3(510) real; L1 output finite, unused
    phaseY<false, false>(&hall[0][0], isL1,
                         A_r1a, A_r1b, A_r2a, A_r2b, A_r3a, A_r3b, A_w1, A_w2, A_w3,
                         &xls[512 * 17], bcol, b1v, w1f, A1h0, A1h1, A1l0, A1l1,
                         bv2, I2h0, I2h1, H2h0, H2h1, H2l0, H2l1,
                         bv3, I3h0, I3h1, H3h0, H3h1, H3l0, H3l1, zc);
    // drain: phase 513 (B): L3(511) -> h3 parity 1; other outputs finite, unused
    phaseY<false, false>(&hall[0][0], isL1,
                         B_r1a, B_r1b, B_r2a, B_r2b, B_r3a, B_r3b, B_w1, B_w2, B_w3,
                         &xls[513 * 17], bcol, b1v, w1f, A1h0, A1h1, A1l0, A1l1,
                         bv2, I2h0, I2h1, H2h0, H2h1, H2l0, H2l1,
                         bv3, I3h0, I3h1, H3h0, H3h1, H3l0, H3l1, zc);

    // ---- FC epilogue: out[b][o] = h3 @ Wfc^T + bfc (h3 single bf16) ----
    if (w < 4) {
        const short* h3f = &hall[5][0];   // h3, parity 1 (phase 513's write)
        int o = (w << 2) | g;             // 0..15, valid < 10
        int b = bcol;
        if (o < 10) {
            float acc = bfc[o];
            for (int k = 0; k < 50; ++k)
                acc += ldsR(h3f, b, k) * Wfc[o * 50 + k];
            out[(size_t)(b0 + b) * 10 + o] = acc;
        }
    }
}

extern "C" void kernel_launch(void* const* d_in, const int* in_sizes, int n_in,
                              void* d_out, int out_size, void* d_ws, size_t ws_size,
                              hipStream_t stream) {
    const float* x    = (const float*)d_in[0];
    const float* Wih1 = (const float*)d_in[1];
    const float* Whh1 = (const float*)d_in[2];
    const float* bih1 = (const float*)d_in[3];
    const float* bhh1 = (const float*)d_in[4];
    const float* Wih2 = (const float*)d_in[5];
    const float* Whh2 = (const float*)d_in[6];
    const float* bih2 = (const float*)d_in[7];
    const float* bhh2 = (const float*)d_in[8];
    const float* Wih3 = (const float*)d_in[9];
    const float* Whh3 = (const float*)d_in[10];
    const float* bih3 = (const float*)d_in[11];
    const float* bhh3 = (const float*)d_in[12];
    const float* Wfc  = (const float*)d_in[13];
    const float* bfc  = (const float*)d_in[14];
    float* out = (float*)d_out;

    dim3 grid(256), block(512);   // 16 batch rows/block; 8 waves = {L1,L23} x stripe
    hipLaunchKernelGGL(rnn3_kernel, grid, block, 0, stream,
                       x, Wih1, Whh1, bih1, bhh1,
                       Wih2, Whh2, bih2, bhh2,
                       Wih3, Whh3, bih3, bhh3,
                       Wfc, bfc, out);
}